// Round 10
// baseline (3194.964 us; speedup 1.0000x reference)
//
#include <hip/hip_runtime.h>
#include <cstdint>
#include <cstddef>

#define NPTS    8192
#define NPT     2048      // NPOINT
#define KNB     32        // NSAMPLE
#define NB      4         // batch
#define DPTS    29        // point feature channels
#define CINP    32        // 3 + 29
#define CO      64        // COUT
#define KS      (KNB*NPT)     // 65536 positions per (b, channel)
#define TELEM   ((size_t)NB*CO*KS)  // 16777216 floats per tensor
#define MCNT    262144.0f     // B*K*S for batch-norm
#define BNEPS   1e-5f
#define FTHR    1024      // FPS threads
#define FWAVES  (FTHR/64) // 16 waves
#define FPT     8         // points per thread (1024*8 = 8192)

// ---------------------------------------------------------------- FPS
// R9 post-mortem: VALU-issue-bound at ~100% of the 4 active CUs (~330
// inst/thread/iter, update is only ~90). R10: EXACT lazy-FPS pruning.
// d[p] only decreases via fmin(d[p], d(p,c)). If a conservative lower bound
// on d(p,c)^2 over a wave's owned points >= the wave's current max d[p],
// the update is a provable no-op -> skip it (update AND wave-reduce; cached
// key/wmax stay valid because d's are unchanged). Margin 0.9999 covers all
// rounding slack (~8 ulp) => skip is conservative-exact, selections cannot
// flip. One-time setup: 4x4x4 Morton-cell counting sort in LDS so each wave
// owns 512 spatially-local points (~0.5-cube bbox via DPP min/max).
// Exact argmax under reordering: per-point tie pass keeps MIN ORIGINAL gidx
// among d_j==tb; wave: f32 DPP max -> readlane(63) -> min-gidx DPP reduce
// among max lanes; u64 key (dist||~gidx) into R9's proven block tree =>
// jnp.argmax first-occurrence semantics preserved bit-exactly.
#define FPS_STEP(J)                                                      \
    {                                                                    \
        float dx = __fsub_rn(px##J, cx);                                 \
        float dy = __fsub_rn(py##J, cy);                                 \
        float dz = __fsub_rn(pz##J, cz);                                 \
        float dd = __fadd_rn(__fadd_rn(__fmul_rn(dx, dx),                \
                                       __fmul_rn(dy, dy)),               \
                             __fmul_rn(dz, dz));                         \
        d##J = fminf(d##J, dd);                                          \
    }

// morton cell of 2 bits/axis (4x4x4 = 64 cells)
#define CELL_OF(X, Y, Z, OUT)                                            \
    {                                                                    \
        int ix = (int)((X) * 4.0f); ix = ix < 0 ? 0 : (ix > 3 ? 3 : ix); \
        int iy = (int)((Y) * 4.0f); iy = iy < 0 ? 0 : (iy > 3 ? 3 : iy); \
        int iz = (int)((Z) * 4.0f); iz = iz < 0 ? 0 : (iz > 3 ? 3 : iz); \
        OUT = (ix & 1) | ((iy & 1) << 1) | ((iz & 1) << 2) |             \
              ((ix & 2) << 2) | ((iy & 2) << 3) | ((iz & 2) << 4);       \
    }

static __device__ __forceinline__ unsigned long long umax64(unsigned long long a,
                                                            unsigned long long b) {
    return a > b ? a : b;
}

// f32 max reduce -> lane 63 (old=0, bound_ctrl=1: 0 neutral for max of >=0;
// exact ctrl sequence HW-validated in R9)
static __device__ __forceinline__ float dppmax_f32_to63(float v) {
    int x = __float_as_int(v), y;
    y = __builtin_amdgcn_update_dpp(0, x, 0x111, 0xf, 0xf, true);
    x = __float_as_int(fmaxf(__int_as_float(x), __int_as_float(y)));
    y = __builtin_amdgcn_update_dpp(0, x, 0x112, 0xf, 0xf, true);
    x = __float_as_int(fmaxf(__int_as_float(x), __int_as_float(y)));
    y = __builtin_amdgcn_update_dpp(0, x, 0x114, 0xf, 0xf, true);
    x = __float_as_int(fmaxf(__int_as_float(x), __int_as_float(y)));
    y = __builtin_amdgcn_update_dpp(0, x, 0x118, 0xf, 0xf, true);
    x = __float_as_int(fmaxf(__int_as_float(x), __int_as_float(y)));
    y = __builtin_amdgcn_update_dpp(0, x, 0x142, 0xa, 0xf, true);
    x = __float_as_int(fmaxf(__int_as_float(x), __int_as_float(y)));
    y = __builtin_amdgcn_update_dpp(0, x, 0x143, 0xc, 0xf, true);
    x = __float_as_int(fmaxf(__int_as_float(x), __int_as_float(y)));
    return __int_as_float(x);
}

// f32 min reduce -> lane 63 (old=self, bound_ctrl=0: invalid/masked lanes
// yield self, neutral for min)
static __device__ __forceinline__ float dppmin_f32_to63(float v) {
    int x = __float_as_int(v), y;
    y = __builtin_amdgcn_update_dpp(x, x, 0x111, 0xf, 0xf, false);
    x = __float_as_int(fminf(__int_as_float(x), __int_as_float(y)));
    y = __builtin_amdgcn_update_dpp(x, x, 0x112, 0xf, 0xf, false);
    x = __float_as_int(fminf(__int_as_float(x), __int_as_float(y)));
    y = __builtin_amdgcn_update_dpp(x, x, 0x114, 0xf, 0xf, false);
    x = __float_as_int(fminf(__int_as_float(x), __int_as_float(y)));
    y = __builtin_amdgcn_update_dpp(x, x, 0x118, 0xf, 0xf, false);
    x = __float_as_int(fminf(__int_as_float(x), __int_as_float(y)));
    y = __builtin_amdgcn_update_dpp(x, x, 0x142, 0xa, 0xf, false);
    x = __float_as_int(fminf(__int_as_float(x), __int_as_float(y)));
    y = __builtin_amdgcn_update_dpp(x, x, 0x143, 0xc, 0xf, false);
    x = __float_as_int(fminf(__int_as_float(x), __int_as_float(y)));
    return __int_as_float(x);
}

// i32 min reduce -> lane 63 (values positive; old=self)
static __device__ __forceinline__ int dppmin_i32_to63(int v) {
    int x = v, y;
    y = __builtin_amdgcn_update_dpp(x, x, 0x111, 0xf, 0xf, false); x = y < x ? y : x;
    y = __builtin_amdgcn_update_dpp(x, x, 0x112, 0xf, 0xf, false); x = y < x ? y : x;
    y = __builtin_amdgcn_update_dpp(x, x, 0x114, 0xf, 0xf, false); x = y < x ? y : x;
    y = __builtin_amdgcn_update_dpp(x, x, 0x118, 0xf, 0xf, false); x = y < x ? y : x;
    y = __builtin_amdgcn_update_dpp(x, x, 0x142, 0xa, 0xf, false); x = y < x ? y : x;
    y = __builtin_amdgcn_update_dpp(x, x, 0x143, 0xc, 0xf, false); x = y < x ? y : x;
    return x;
}

__global__ __launch_bounds__(FTHR, 1)
void fps_kernel(const float* __restrict__ xyz,
                float* __restrict__ out0) {
    const int b = blockIdx.x;
    const int t = threadIdx.x;          // 0..1023
    const int lane = t & 63;
    const int wid  = t >> 6;            // 0..15
    const float* xb = xyz + (size_t)b * 3 * NPTS;
    const int base = t * FPT;

    // LDS layout (131,584 B total):
    //   sx/sy/sz cloud copy (96 KB, original index order)
    //   region (32 KB): setup = sgid[8192] (j-major: sgid[j*1024+t]);
    //                   loop  = so[3][NPT] (24 KB) + skey[2][16] (256 B)
    //   scnt[64] + soff[64]
    extern __shared__ float smem[];
    float* sx = smem;
    float* sy = sx + NPTS;
    float* sz = sy + NPTS;
    int*   region = (int*)(sz + NPTS);
    int*   sgid = region;
    float* so   = (float*)region;
    unsigned long long* skey = (unsigned long long*)((float*)region + 3 * NPT);
    int* scnt = region + NPTS;
    int* soff = scnt + 64;

    // ---- setup phase 1: stage cloud into LDS; keep original chunk in regs
    float4 vx0, vx1, vy0, vy1, vz0, vz1;
    {
        const float4* x4 = (const float4*)(xb + base);
        const float4* y4 = (const float4*)(xb + NPTS + base);
        const float4* z4 = (const float4*)(xb + 2 * NPTS + base);
        float4* lx4 = (float4*)(sx + base);
        float4* ly4 = (float4*)(sy + base);
        float4* lz4 = (float4*)(sz + base);
        vx0 = x4[0]; lx4[0] = vx0;  vx1 = x4[1]; lx4[1] = vx1;
        vy0 = y4[0]; ly4[0] = vy0;  vy1 = y4[1]; ly4[1] = vy1;
        vz0 = z4[0]; lz4[0] = vz0;  vz1 = z4[1]; lz4[1] = vz1;
    }
    if (t < 64) scnt[t] = 0;
    __syncthreads();

    // ---- setup phase 2: counting sort by morton cell
#define P_CNT(PX, PY, PZ) { int cc; CELL_OF(PX, PY, PZ, cc); atomicAdd(&scnt[cc], 1); }
    P_CNT(vx0.x, vy0.x, vz0.x) P_CNT(vx0.y, vy0.y, vz0.y)
    P_CNT(vx0.z, vy0.z, vz0.z) P_CNT(vx0.w, vy0.w, vz0.w)
    P_CNT(vx1.x, vy1.x, vz1.x) P_CNT(vx1.y, vy1.y, vz1.y)
    P_CNT(vx1.z, vy1.z, vz1.z) P_CNT(vx1.w, vy1.w, vz1.w)
    __syncthreads();
    if (t == 0) {           // serial exclusive prefix over 64 cells (one-time)
        int off = 0;
        for (int c2 = 0; c2 < 64; ++c2) { int n = scnt[c2]; soff[c2] = off; off += n; }
    }
    __syncthreads();
#define P_SCAT(PX, PY, PZ, GI)                                           \
    { int cc; CELL_OF(PX, PY, PZ, cc);                                   \
      int pos = atomicAdd(&soff[cc], 1);                                 \
      sgid[((pos & 7) << 10) + (pos >> 3)] = (GI); }
    P_SCAT(vx0.x, vy0.x, vz0.x, base + 0) P_SCAT(vx0.y, vy0.y, vz0.y, base + 1)
    P_SCAT(vx0.z, vy0.z, vz0.z, base + 2) P_SCAT(vx0.w, vy0.w, vz0.w, base + 3)
    P_SCAT(vx1.x, vy1.x, vz1.x, base + 4) P_SCAT(vx1.y, vy1.y, vz1.y, base + 5)
    P_SCAT(vx1.z, vy1.z, vz1.z, base + 6) P_SCAT(vx1.w, vy1.w, vz1.w, base + 7)
    __syncthreads();

    // ---- setup phase 3: gather my 8 owned (spatially local) points
    int g0 = sgid[0*1024 + t], g1 = sgid[1*1024 + t],
        g2 = sgid[2*1024 + t], g3 = sgid[3*1024 + t],
        g4 = sgid[4*1024 + t], g5 = sgid[5*1024 + t],
        g6 = sgid[6*1024 + t], g7 = sgid[7*1024 + t];
    float px0 = sx[g0], py0 = sy[g0], pz0 = sz[g0];
    float px1 = sx[g1], py1 = sy[g1], pz1 = sz[g1];
    float px2 = sx[g2], py2 = sy[g2], pz2 = sz[g2];
    float px3 = sx[g3], py3 = sy[g3], pz3 = sz[g3];
    float px4 = sx[g4], py4 = sy[g4], pz4 = sz[g4];
    float px5 = sx[g5], py5 = sy[g5], pz5 = sz[g5];
    float px6 = sx[g6], py6 = sy[g6], pz6 = sz[g6];
    float px7 = sx[g7], py7 = sy[g7], pz7 = sz[g7];
    float d0, d1, d2, d3, d4, d5, d6, d7;
    d0 = d1 = d2 = d3 = d4 = d5 = d6 = d7 = 1e10f;

    // wave bbox (of owned points) -> wave-uniform scalars
    float mnx = fminf(fminf(fminf(px0,px1),fminf(px2,px3)),fminf(fminf(px4,px5),fminf(px6,px7)));
    float mxx = fmaxf(fmaxf(fmaxf(px0,px1),fmaxf(px2,px3)),fmaxf(fmaxf(px4,px5),fmaxf(px6,px7)));
    float mny = fminf(fminf(fminf(py0,py1),fminf(py2,py3)),fminf(fminf(py4,py5),fminf(py6,py7)));
    float mxy = fmaxf(fmaxf(fmaxf(py0,py1),fmaxf(py2,py3)),fmaxf(fmaxf(py4,py5),fmaxf(py6,py7)));
    float mnz = fminf(fminf(fminf(pz0,pz1),fminf(pz2,pz3)),fminf(fminf(pz4,pz5),fminf(pz6,pz7)));
    float mxz = fmaxf(fmaxf(fmaxf(pz0,pz1),fmaxf(pz2,pz3)),fmaxf(fmaxf(pz4,pz5),fmaxf(pz6,pz7)));
    const float bminx = __int_as_float(__builtin_amdgcn_readlane(__float_as_int(dppmin_f32_to63(mnx)), 63));
    const float bmaxx = __int_as_float(__builtin_amdgcn_readlane(__float_as_int(dppmax_f32_to63(mxx)), 63));
    const float bminy = __int_as_float(__builtin_amdgcn_readlane(__float_as_int(dppmin_f32_to63(mny)), 63));
    const float bmaxy = __int_as_float(__builtin_amdgcn_readlane(__float_as_int(dppmax_f32_to63(mxy)), 63));
    const float bminz = __int_as_float(__builtin_amdgcn_readlane(__float_as_int(dppmin_f32_to63(mnz)), 63));
    const float bmaxz = __int_as_float(__builtin_amdgcn_readlane(__float_as_int(dppmax_f32_to63(mxz)), 63));

    __syncthreads();   // all sgid reads done; region becomes so/skey

    // initial centroid = point 0 (broadcast global load)
    float cx = xb[0], cy = xb[NPTS], cz = xb[2 * NPTS];
    if (t == 0) { so[0] = cx; so[NPT] = cy; so[2 * NPT] = cz; }

    float wmax = 3.0e38f;                 // force full update on iter 1
    unsigned long long kpack = 0;

    for (int i = 1; i < NPT; ++i) {
        // conservative lower bound on d(p,c)^2 over this wave's points
        float ddx = fmaxf(fmaxf(bminx - cx, cx - bmaxx), 0.0f);
        float ddy = fmaxf(fmaxf(bminy - cy, cy - bmaxy), 0.0f);
        float ddz = fmaxf(fmaxf(bminz - cz, cz - bmaxz), 0.0f);
        float bd2 = ddx * ddx + ddy * ddy + ddz * ddz;
        if (!(bd2 * 0.9999f >= wmax)) {   // wave-uniform branch
            FPS_STEP(0) FPS_STEP(1) FPS_STEP(2) FPS_STEP(3)
            FPS_STEP(4) FPS_STEP(5) FPS_STEP(6) FPS_STEP(7)
            float tb = fmaxf(fmaxf(fmaxf(d0,d1),fmaxf(d2,d3)),
                             fmaxf(fmaxf(d4,d5),fmaxf(d6,d7)));
            int bg = 0x7fffffff;          // min ORIGINAL gidx among d_j == tb
            if (d0 == tb) bg = g0 < bg ? g0 : bg;
            if (d1 == tb) bg = g1 < bg ? g1 : bg;
            if (d2 == tb) bg = g2 < bg ? g2 : bg;
            if (d3 == tb) bg = g3 < bg ? g3 : bg;
            if (d4 == tb) bg = g4 < bg ? g4 : bg;
            if (d5 == tb) bg = g5 < bg ? g5 : bg;
            if (d6 == tb) bg = g6 < bg ? g6 : bg;
            if (d7 == tb) bg = g7 < bg ? g7 : bg;
            float wm_s = __int_as_float(
                __builtin_amdgcn_readlane(__float_as_int(dppmax_f32_to63(tb)), 63));
            int cand = (tb == wm_s) ? bg : 0x7fffffff;
            int wgid = __builtin_amdgcn_readlane(dppmin_i32_to63(cand), 63);
            wmax = wm_s;
            kpack = (((unsigned long long)__float_as_uint(wm_s)) << 32) |
                    (unsigned)(~(unsigned)wgid);
        }
        const int par = i & 1;
        if (lane == 63) skey[par * FWAVES + wid] = kpack;
        __syncthreads();

        // block reduce: broadcast-read all 16 wave keys, register max tree
        const ulonglong2* sk2 = (const ulonglong2*)(skey + par * FWAVES);
        ulonglong2 k0 = sk2[0], k1 = sk2[1], k2 = sk2[2], k3 = sk2[3];
        ulonglong2 k4 = sk2[4], k5 = sk2[5], k6 = sk2[6], k7 = sk2[7];
        unsigned long long m0 = umax64(k0.x, k0.y);
        unsigned long long m1 = umax64(k1.x, k1.y);
        unsigned long long m2 = umax64(k2.x, k2.y);
        unsigned long long m3 = umax64(k3.x, k3.y);
        unsigned long long m4 = umax64(k4.x, k4.y);
        unsigned long long m5 = umax64(k5.x, k5.y);
        unsigned long long m6 = umax64(k6.x, k6.y);
        unsigned long long m7 = umax64(k7.x, k7.y);
        unsigned long long kbest = umax64(umax64(umax64(m0, m1), umax64(m2, m3)),
                                          umax64(umax64(m4, m5), umax64(m6, m7)));
        const int widx = (int)(~(unsigned int)kbest);

        // broadcast coord fetch from LDS cloud copy (original layout)
        cx = sx[widx]; cy = sy[widx]; cz = sz[widx];
        if (t == 0) { so[i] = cx; so[NPT + i] = cy; so[2 * NPT + i] = cz; }
        // no 2nd barrier: skey parity double-buffered; so[i] write-once
    }

    __syncthreads();
    // flush staged out0 (3,2048) — coalesced, once
    float* ob = out0 + (size_t)b * 3 * NPT;
    for (int r = t; r < 3 * NPT; r += FTHR) ob[r] = so[r];
}

// ---------------------------------------------------------------- ball query
// One wave per (b, s). 32 smallest in-radius indices (ascending scan +
// ballot compaction), padded with the first hit.
__global__ __launch_bounds__(256) void ballq_kernel(const float* __restrict__ xyz,
                                                    const float* __restrict__ out0,
                                                    int* __restrict__ idx) {
    const int gw   = (blockIdx.x * 256 + threadIdx.x) >> 6;  // 0..8191
    const int lane = threadIdx.x & 63;
    const int b  = gw >> 11;
    const int si = gw & 2047;
    const float* xb = xyz + (size_t)b * 3 * NPTS;

    const float cx = out0[b * 3 * NPT + si];
    const float cy = out0[b * 3 * NPT + NPT + si];
    const float cz = out0[b * 3 * NPT + 2*NPT + si];
    const float csum = __fadd_rn(__fadd_rn(__fmul_rn(cx, cx), __fmul_rn(cy, cy)),
                                 __fmul_rn(cz, cz));
    const float R2 = (float)(0.1 * 0.1);  // 0x3C23D70A — NOT 0.1f*0.1f!

    __shared__ int buf[4][KNB];
    int* mybuf = buf[threadIdx.x >> 6];

    int cnt = 0;
    for (int n0 = 0; n0 < NPTS && cnt < KNB; n0 += 64) {
        const int i = n0 + lane;
        float pxv = xb[i], pyv = xb[NPTS + i], pzv = xb[2 * NPTS + i];
        float ps = __fadd_rn(__fadd_rn(__fmul_rn(pxv, pxv), __fmul_rn(pyv, pyv)),
                             __fmul_rn(pzv, pzv));
        float dot = __fmaf_rn(pzv, cz, __fmaf_rn(pyv, cy, __fmul_rn(pxv, cx)));
        float sqr = __fsub_rn(__fadd_rn(csum, ps), __fadd_rn(dot, dot));
        bool hit = (sqr <= R2);
        unsigned long long m = __ballot(hit);
        int pos = cnt + __popcll(m & ((1ull << lane) - 1ull));
        if (hit && pos < KNB) mybuf[pos] = i;
        cnt += __popcll(m);
    }
    __syncthreads();
    int c = cnt < KNB ? cnt : KNB;
    int first = (cnt > 0) ? mybuf[0] : 0;
    if (lane < KNB) {
        int v = (lane < c) ? mybuf[lane] : first;
        idx[((size_t)gw << 5) + lane] = v;
    }
}

// ---------------------------------------------------------------- proj conv
// Fused gather/concat + conv(32->64) + BN-stats accumulation.
__global__ __launch_bounds__(256) void proj_kernel(const float* __restrict__ xyz,
                                                   const float* __restrict__ points,
                                                   const float* __restrict__ out0,
                                                   const int* __restrict__ idx,
                                                   const float* __restrict__ W,
                                                   float* __restrict__ out,
                                                   float* __restrict__ stats) {
    const int p = blockIdx.x * 256 + threadIdx.x;   // 0..262143
    const int b = p >> 16;
    const int q = p & 65535;       // k*NPT + s
    const int k = q >> 11;
    const int s = q & 2047;
    const int tid = threadIdx.x;

    __shared__ float ssum[CO], ssq[CO];
    if (tid < CO) { ssum[tid] = 0.f; ssq[tid] = 0.f; }
    __syncthreads();

    const int j = idx[((size_t)(b * NPT + s) << 5) + k];
    const float* xb = xyz + (size_t)b * 3 * NPTS;
    float a[CINP];
    a[0] = xb[j]            - out0[b * 3 * NPT + s];
    a[1] = xb[NPTS + j]     - out0[b * 3 * NPT + NPT + s];
    a[2] = xb[2*NPTS + j]   - out0[b * 3 * NPT + 2*NPT + s];
    const float* pb = points + (size_t)b * DPTS * NPTS;
#pragma unroll
    for (int c = 0; c < DPTS; ++c) a[3 + c] = pb[c * NPTS + j];

    const size_t obase = (size_t)b * CO * KS + q;
    for (int o = 0; o < CO; ++o) {
        float acc = 0.f;
#pragma unroll
        for (int c = 0; c < CINP; ++c) acc = __fmaf_rn(W[o * CINP + c], a[c], acc);
        out[obase + (size_t)o * KS] = acc;
        float s1 = acc, s2 = acc * acc;
#pragma unroll
        for (int off = 32; off > 0; off >>= 1) {
            s1 += __shfl_xor(s1, off, 64);
            s2 += __shfl_xor(s2, off, 64);
        }
        if ((tid & 63) == 0) { atomicAdd(&ssum[o], s1); atomicAdd(&ssq[o], s2); }
    }
    __syncthreads();
    if (tid < CO) {
        atomicAdd(&stats[tid], ssum[tid]);
        atomicAdd(&stats[CO + tid], ssq[tid]);
    }
}

// ---------------------------------------------------------------- fused conv
// input-BN (+optional residual) + relu -> GEMM 64x64 -> raw out + stats.
// NOTE: in/idn/act_out/out may ALIAS (in-place use): no __restrict__ on them.
template <bool HAS_IDN, bool WRITE_ACT>
__global__ __launch_bounds__(256) void conv_bn_kernel(const float* in,
                                                      const float* idn,
                                                      const float* __restrict__ stats_in,
                                                      const float* __restrict__ gamma,
                                                      const float* __restrict__ beta,
                                                      const float* __restrict__ W,
                                                      float* act_out,
                                                      float* out,
                                                      float* __restrict__ stats_out) {
    const int p = blockIdx.x * 256 + threadIdx.x;
    const int b = p >> 16;
    const int q = p & 65535;
    const int tid = threadIdx.x;

    __shared__ float ssc[CO], ssh[CO], ssum[CO], ssq[CO];
    if (tid < CO) {
        const float Minv = 1.0f / MCNT;
        float m = stats_in[tid] * Minv;
        float v = stats_in[CO + tid] * Minv - m * m;
        float scl = gamma[tid] * rsqrtf(v + BNEPS);
        ssc[tid] = scl;
        ssh[tid] = beta[tid] - m * scl;
        ssum[tid] = 0.f; ssq[tid] = 0.f;
    }
    __syncthreads();

    const size_t base = (size_t)b * CO * KS + q;
    float a[CO];
#pragma unroll
    for (int c = 0; c < CO; ++c) {
        float v = __fmaf_rn(ssc[c], in[base + (size_t)c * KS], ssh[c]);
        if (HAS_IDN) v += idn[base + (size_t)c * KS];
        v = fmaxf(v, 0.0f);
        a[c] = v;
        if (WRITE_ACT) act_out[base + (size_t)c * KS] = v;
    }
    for (int o = 0; o < CO; ++o) {
        float acc = 0.f;
#pragma unroll
        for (int c = 0; c < CO; ++c) acc = __fmaf_rn(W[o * CO + c], a[c], acc);
        out[base + (size_t)o * KS] = acc;
        float s1 = acc, s2 = acc * acc;
#pragma unroll
        for (int off = 32; off > 0; off >>= 1) {
            s1 += __shfl_xor(s1, off, 64);
            s2 += __shfl_xor(s2, off, 64);
        }
        if ((tid & 63) == 0) { atomicAdd(&ssum[o], s1); atomicAdd(&ssq[o], s2); }
    }
    __syncthreads();
    if (tid < CO) {
        atomicAdd(&stats_out[tid], ssum[tid]);
        atomicAdd(&stats_out[CO + tid], ssq[tid]);
    }
}

// ---------------------------------------------------------------- final
// BN + residual + relu + maxpool over k.
__global__ __launch_bounds__(256) void final_kernel(const float* __restrict__ y2,
                                                    const float* __restrict__ idn,
                                                    const float* __restrict__ stats,
                                                    const float* __restrict__ gamma,
                                                    const float* __restrict__ beta,
                                                    float* __restrict__ feat) {
    const int p = blockIdx.x * 256 + threadIdx.x;   // 0..524287
    const int s = p & 2047;
    const int o = (p >> 11) & 63;
    const int b = p >> 17;
    const float Minv = 1.0f / MCNT;
    float m = stats[o] * Minv;
    float v = stats[CO + o] * Minv - m * m;
    float scl = gamma[o] * rsqrtf(v + BNEPS);
    float sh  = beta[o] - m * scl;
    const size_t base = (size_t)b * CO * KS + (size_t)o * KS + s;
    float mx = -1e30f;
#pragma unroll
    for (int k = 0; k < KNB; ++k) {
        float val = __fmaf_rn(scl, y2[base + (size_t)k * NPT], sh) + idn[base + (size_t)k * NPT];
        val = fmaxf(val, 0.0f);
        mx = fmaxf(mx, val);
    }
    feat[p] = mx;
}

__global__ void zero_kernel(float* p, int n) {
    int i = blockIdx.x * blockDim.x + threadIdx.x;
    if (i < n) p[i] = 0.f;
}

extern "C" void kernel_launch(void* const* d_in, const int* in_sizes, int n_in,
                              void* d_out, int out_size, void* d_ws, size_t ws_size,
                              hipStream_t stream) {
    (void)in_sizes; (void)n_in; (void)out_size; (void)ws_size;
    const float* xyz    = (const float*)d_in[0];
    const float* points = (const float*)d_in[1];
    const float* proj_w = (const float*)d_in[2];
    const float* proj_g = (const float*)d_in[3];
    const float* proj_b = (const float*)d_in[4];
    const float* w1     = (const float*)d_in[5];   // (2,64,64)
    const float* g1     = (const float*)d_in[6];
    const float* b1     = (const float*)d_in[7];
    const float* w2     = (const float*)d_in[8];
    const float* g2     = (const float*)d_in[9];
    const float* b2     = (const float*)d_in[10];

    float* out0 = (float*)d_out;                   // (4,3,2048)
    float* feat = (float*)d_out + NB * 3 * NPT;    // (4,64,2048)

    float* stats = (float*)d_ws;                    // 5 x 128 (rounded to 1024)
    int*   idx   = (int*)((float*)d_ws + 1024);     // (4,2048,32)
    float* A     = (float*)(idx + NB * NPT * KNB);  // activation tensor
    float* B     = A + TELEM;                       // residual tensor

    // fps LDS: cloud 96K + region 32K (sgid / so+skey overlay) + scnt/soff
    const size_t fps_lds = (size_t)(3 * NPTS) * sizeof(float)
                         + (size_t)NPTS * sizeof(int)
                         + 128 * sizeof(int);       // 131,584 B

    hipLaunchKernelGGL(zero_kernel, dim3(3), dim3(256), 0, stream, stats, 5 * 2 * CO);
    hipLaunchKernelGGL(fps_kernel, dim3(NB), dim3(FTHR), fps_lds, stream, xyz, out0);
    hipLaunchKernelGGL(ballq_kernel, dim3(2048), dim3(256), 0, stream, xyz, out0, idx);
    // proj raw conv -> A, stats0
    hipLaunchKernelGGL(proj_kernel, dim3(1024), dim3(256), 0, stream,
                       xyz, points, out0, idx, proj_w, A, stats);
    // d=0: x = relu(bnP(A)); idn0 -> B; y1 -> A (in-place)
    hipLaunchKernelGGL((conv_bn_kernel<false, true>), dim3(1024), dim3(256), 0, stream,
                       A, (const float*)nullptr, stats, proj_g, proj_b, w1,
                       B, A, stats + 128);
    // d=0: y2 = conv(w2[0], relu(bn1(y1)))  A -> A
    hipLaunchKernelGGL((conv_bn_kernel<false, false>), dim3(1024), dim3(256), 0, stream,
                       A, (const float*)nullptr, stats + 128, g1, b1, w2,
                       (float*)nullptr, A, stats + 256);
    // d=1: x = relu(bn2(y2)+idn0); idn1 -> B (aliases idn read); y1 -> A
    hipLaunchKernelGGL((conv_bn_kernel<true, true>), dim3(1024), dim3(256), 0, stream,
                       A, B, stats + 256, g2, b2, w1 + CO * CO,
                       B, A, stats + 384);
    // d=1: y2 = conv(w2[1], relu(bn1'(y1)))  A -> A
    hipLaunchKernelGGL((conv_bn_kernel<false, false>), dim3(1024), dim3(256), 0, stream,
                       A, (const float*)nullptr, stats + 384, g1 + CO, b1 + CO, w2 + CO * CO,
                       (float*)nullptr, A, stats + 512);
    // feat = max_k relu(bn2'(A)+B)
    hipLaunchKernelGGL(final_kernel, dim3(2048), dim3(256), 0, stream,
                       A, B, stats + 512, g2 + CO, b2 + CO, feat);
}

// Round 11
// 3153.466 us; speedup vs baseline: 1.0132x; 1.0132x over previous
//
#include <hip/hip_runtime.h>
#include <cstdint>
#include <cstddef>

#define NPTS    8192
#define NPT     2048      // NPOINT
#define KNB     32        // NSAMPLE
#define NB      4         // batch
#define DPTS    29        // point feature channels
#define CINP    32        // 3 + 29
#define CO      64        // COUT
#define KS      (KNB*NPT)     // 65536 positions per (b, channel)
#define TELEM   ((size_t)NB*CO*KS)  // 16777216 floats per tensor
#define MCNT    262144.0f     // B*K*S for batch-norm
#define BNEPS   1e-5f
#define FTHR    1024      // FPS threads
#define FWAVES  (FTHR/64) // 16 waves
#define FPT     8         // points per thread (1024*8 = 8192)

// ---------------------------------------------------------------- FPS
// R10 post-mortem: lazy skipping halved VALU issue but time ROSE — the
// iteration floor is the slowest wave's critical path, not total issue.
// R11 = R9 substrate (sort/lazy reverted) + two critical-path cuts:
//  1) packed-FP32 update: v_pk_add/mul_f32 (VOP3P) process 2 points/inst
//     with bit-identical IEEE rounding per half. Sub done as px + (-cx)
//     (exact: same rounded value as px - cx). fmin + argmax stay scalar.
//  2) block tree computed by wave 0 ONLY (was redundant in all 16 waves):
//     keys -> barrier -> wave0 tree + coord fetch -> post {cx,cy,cz} ->
//     barrier -> all read 3 broadcast floats. skey single-buffered (the
//     two barriers order writes/reads).
// Numerics: update ops are IEEE-identical to np's ((dx^2+dy^2)+dz^2);
// tb = fmax tree (assoc/comm, equal result); jj descending scan keeps
// FIRST (lowest j) max; u64 key (dist||~gidx) + wave/blocked max =>
// jnp.argmax first-occurrence semantics bit-exact.
typedef float v2f __attribute__((ext_vector_type(2)));

static __device__ __forceinline__ v2f pk_add(v2f a, v2f b) {
    v2f d;
    asm("v_pk_add_f32 %0, %1, %2" : "=v"(d) : "v"(a), "v"(b));
    return d;
}
static __device__ __forceinline__ v2f pk_mul(v2f a, v2f b) {
    v2f d;
    asm("v_pk_mul_f32 %0, %1, %2" : "=v"(d) : "v"(a), "v"(b));
    return d;
}

#define FPS_PAIR(J)                                                      \
    {                                                                    \
        v2f dx = pk_add(px##J, cvx);                                     \
        v2f dy = pk_add(py##J, cvy);                                     \
        v2f dz = pk_add(pz##J, cvz);                                     \
        v2f dd = pk_add(pk_add(pk_mul(dx, dx), pk_mul(dy, dy)),          \
                        pk_mul(dz, dz));                                 \
        d##J.x = fminf(d##J.x, dd.x);                                    \
        d##J.y = fminf(d##J.y, dd.y);                                    \
    }

// one DPP max step on a u64 key (2x v_mov_dpp + 64-bit cmp/select) [R9-proven]
#define DPP64_MAX(k, ctrl, rmask)                                               \
    {                                                                           \
        unsigned _lo = (unsigned)(k);                                           \
        unsigned _hi = (unsigned)((k) >> 32);                                   \
        _lo = (unsigned)__builtin_amdgcn_update_dpp(0, (int)_lo, ctrl, rmask, 0xf, true); \
        _hi = (unsigned)__builtin_amdgcn_update_dpp(0, (int)_hi, ctrl, rmask, 0xf, true); \
        unsigned long long _k2 = ((unsigned long long)_hi << 32) | _lo;         \
        k = (_k2 > k) ? _k2 : k;                                                \
    }

static __device__ __forceinline__ unsigned long long umax64(unsigned long long a,
                                                            unsigned long long b) {
    return a > b ? a : b;
}

__global__ __launch_bounds__(FTHR, 1)
void fps_kernel(const float* __restrict__ xyz,
                float* __restrict__ out0) {
    const int b = blockIdx.x;
    const int t = threadIdx.x;          // 0..1023
    const int lane = t & 63;
    const int wid  = t >> 6;            // 0..15
    const float* xb = xyz + (size_t)b * 3 * NPTS;
    const int base = t * FPT;

    // LDS: sx/sy/sz cloud (96 KB) + so[3][NPT] (24 KB) + skey[16] + swin[4]
    extern __shared__ float smem[];
    float* sx = smem;
    float* sy = sx + NPTS;
    float* sz = sy + NPTS;
    float* so = sz + NPTS;
    unsigned long long* skey = (unsigned long long*)(so + 3 * NPT);
    float* swin = (float*)(skey + FWAVES);

    // 8 points/thread in 12 v2f coord pairs + 4 v2f dist pairs (VGPR-resident)
    v2f px01, px23, px45, px67, py01, py23, py45, py67, pz01, pz23, pz45, pz67;
    v2f d01, d23, d45, d67;
    {
        const float4* x4 = (const float4*)(xb + base);
        const float4* y4 = (const float4*)(xb + NPTS + base);
        const float4* z4 = (const float4*)(xb + 2 * NPTS + base);
        float4* lx4 = (float4*)(sx + base);
        float4* ly4 = (float4*)(sy + base);
        float4* lz4 = (float4*)(sz + base);
        float4 v;
        v = x4[0]; lx4[0] = v; px01 = (v2f){v.x, v.y}; px23 = (v2f){v.z, v.w};
        v = x4[1]; lx4[1] = v; px45 = (v2f){v.x, v.y}; px67 = (v2f){v.z, v.w};
        v = y4[0]; ly4[0] = v; py01 = (v2f){v.x, v.y}; py23 = (v2f){v.z, v.w};
        v = y4[1]; ly4[1] = v; py45 = (v2f){v.x, v.y}; py67 = (v2f){v.z, v.w};
        v = z4[0]; lz4[0] = v; pz01 = (v2f){v.x, v.y}; pz23 = (v2f){v.z, v.w};
        v = z4[1]; lz4[1] = v; pz45 = (v2f){v.x, v.y}; pz67 = (v2f){v.z, v.w};
        d01 = d23 = d45 = d67 = (v2f){1e10f, 1e10f};
    }

    // initial centroid = point 0 (broadcast global load)
    float cx = xb[0], cy = xb[NPTS], cz = xb[2 * NPTS];
    if (t == 0) { so[0] = cx; so[NPT] = cy; so[2 * NPT] = cz; }
    // staging barrier folded into iteration-1's first barrier (sx first read
    // by wave0 after that barrier).

    for (int i = 1; i < NPT; ++i) {
        // negate once (exact); px + (-cx) rounds identically to px - cx
        const float ncx = -cx, ncy = -cy, ncz = -cz;
        const v2f cvx = (v2f){ncx, ncx};
        const v2f cvy = (v2f){ncy, ncy};
        const v2f cvz = (v2f){ncz, ncz};
        FPS_PAIR(01) FPS_PAIR(23) FPS_PAIR(45) FPS_PAIR(67)

        // thread max + FIRST-occurrence index (descending scan)
        float tb = fmaxf(fmaxf(fmaxf(d01.x, d01.y), fmaxf(d23.x, d23.y)),
                         fmaxf(fmaxf(d45.x, d45.y), fmaxf(d67.x, d67.y)));
        int jj = 7;
        if (d67.x == tb) jj = 6;
        if (d45.y == tb) jj = 5;
        if (d45.x == tb) jj = 4;
        if (d23.y == tb) jj = 3;
        if (d23.x == tb) jj = 2;
        if (d01.y == tb) jj = 1;
        if (d01.x == tb) jj = 0;

        // u64 key: larger dist wins; ties -> lower global index
        unsigned long long k =
            (((unsigned long long)__float_as_uint(tb)) << 32) |
            (unsigned int)(~(unsigned int)(base + jj));
        DPP64_MAX(k, 0x111, 0xf)   // row_shr:1
        DPP64_MAX(k, 0x112, 0xf)   // row_shr:2
        DPP64_MAX(k, 0x114, 0xf)   // row_shr:4
        DPP64_MAX(k, 0x118, 0xf)   // row_shr:8
        DPP64_MAX(k, 0x142, 0xa)   // row_bcast:15
        DPP64_MAX(k, 0x143, 0xc)   // row_bcast:31 -> lane63 = wave max
        if (lane == 63) skey[wid] = k;
        __syncthreads();

        // wave 0 ONLY: block tree over 16 keys + coord fetch + post winner
        if (wid == 0) {
            const ulonglong2* sk2 = (const ulonglong2*)skey;
            ulonglong2 k0 = sk2[0], k1 = sk2[1], k2 = sk2[2], k3 = sk2[3];
            ulonglong2 k4 = sk2[4], k5 = sk2[5], k6 = sk2[6], k7 = sk2[7];
            unsigned long long m0 = umax64(k0.x, k0.y);
            unsigned long long m1 = umax64(k1.x, k1.y);
            unsigned long long m2 = umax64(k2.x, k2.y);
            unsigned long long m3 = umax64(k3.x, k3.y);
            unsigned long long m4 = umax64(k4.x, k4.y);
            unsigned long long m5 = umax64(k5.x, k5.y);
            unsigned long long m6 = umax64(k6.x, k6.y);
            unsigned long long m7 = umax64(k7.x, k7.y);
            unsigned long long kbest = umax64(umax64(umax64(m0, m1), umax64(m2, m3)),
                                              umax64(umax64(m4, m5), umax64(m6, m7)));
            const int widx = (int)(~(unsigned int)kbest);
            float wx = sx[widx], wy = sy[widx], wz = sz[widx];  // broadcast
            if (t == 0) {
                swin[0] = wx; swin[1] = wy; swin[2] = wz;
                so[i] = wx; so[NPT + i] = wy; so[2 * NPT + i] = wz;
            }
        }
        __syncthreads();
        cx = swin[0]; cy = swin[1]; cz = swin[2];   // broadcast reads
    }

    __syncthreads();
    // flush staged out0 (3,2048) — coalesced, once
    float* ob = out0 + (size_t)b * 3 * NPT;
    for (int r = t; r < 3 * NPT; r += FTHR) ob[r] = so[r];
}

// ---------------------------------------------------------------- ball query
// One wave per (b, s). 32 smallest in-radius indices (ascending scan +
// ballot compaction), padded with the first hit.
__global__ __launch_bounds__(256) void ballq_kernel(const float* __restrict__ xyz,
                                                    const float* __restrict__ out0,
                                                    int* __restrict__ idx) {
    const int gw   = (blockIdx.x * 256 + threadIdx.x) >> 6;  // 0..8191
    const int lane = threadIdx.x & 63;
    const int b  = gw >> 11;
    const int si = gw & 2047;
    const float* xb = xyz + (size_t)b * 3 * NPTS;

    const float cx = out0[b * 3 * NPT + si];
    const float cy = out0[b * 3 * NPT + NPT + si];
    const float cz = out0[b * 3 * NPT + 2*NPT + si];
    const float csum = __fadd_rn(__fadd_rn(__fmul_rn(cx, cx), __fmul_rn(cy, cy)),
                                 __fmul_rn(cz, cz));
    const float R2 = (float)(0.1 * 0.1);  // 0x3C23D70A — NOT 0.1f*0.1f!

    __shared__ int buf[4][KNB];
    int* mybuf = buf[threadIdx.x >> 6];

    int cnt = 0;
    for (int n0 = 0; n0 < NPTS && cnt < KNB; n0 += 64) {
        const int i = n0 + lane;
        float pxv = xb[i], pyv = xb[NPTS + i], pzv = xb[2 * NPTS + i];
        float ps = __fadd_rn(__fadd_rn(__fmul_rn(pxv, pxv), __fmul_rn(pyv, pyv)),
                             __fmul_rn(pzv, pzv));
        float dot = __fmaf_rn(pzv, cz, __fmaf_rn(pyv, cy, __fmul_rn(pxv, cx)));
        float sqr = __fsub_rn(__fadd_rn(csum, ps), __fadd_rn(dot, dot));
        bool hit = (sqr <= R2);
        unsigned long long m = __ballot(hit);
        int pos = cnt + __popcll(m & ((1ull << lane) - 1ull));
        if (hit && pos < KNB) mybuf[pos] = i;
        cnt += __popcll(m);
    }
    __syncthreads();
    int c = cnt < KNB ? cnt : KNB;
    int first = (cnt > 0) ? mybuf[0] : 0;
    if (lane < KNB) {
        int v = (lane < c) ? mybuf[lane] : first;
        idx[((size_t)gw << 5) + lane] = v;
    }
}

// ---------------------------------------------------------------- proj conv
// Fused gather/concat + conv(32->64) + BN-stats accumulation.
__global__ __launch_bounds__(256) void proj_kernel(const float* __restrict__ xyz,
                                                   const float* __restrict__ points,
                                                   const float* __restrict__ out0,
                                                   const int* __restrict__ idx,
                                                   const float* __restrict__ W,
                                                   float* __restrict__ out,
                                                   float* __restrict__ stats) {
    const int p = blockIdx.x * 256 + threadIdx.x;   // 0..262143
    const int b = p >> 16;
    const int q = p & 65535;       // k*NPT + s
    const int k = q >> 11;
    const int s = q & 2047;
    const int tid = threadIdx.x;

    __shared__ float ssum[CO], ssq[CO];
    if (tid < CO) { ssum[tid] = 0.f; ssq[tid] = 0.f; }
    __syncthreads();

    const int j = idx[((size_t)(b * NPT + s) << 5) + k];
    const float* xb = xyz + (size_t)b * 3 * NPTS;
    float a[CINP];
    a[0] = xb[j]            - out0[b * 3 * NPT + s];
    a[1] = xb[NPTS + j]     - out0[b * 3 * NPT + NPT + s];
    a[2] = xb[2*NPTS + j]   - out0[b * 3 * NPT + 2*NPT + s];
    const float* pb = points + (size_t)b * DPTS * NPTS;
#pragma unroll
    for (int c = 0; c < DPTS; ++c) a[3 + c] = pb[c * NPTS + j];

    const size_t obase = (size_t)b * CO * KS + q;
    for (int o = 0; o < CO; ++o) {
        float acc = 0.f;
#pragma unroll
        for (int c = 0; c < CINP; ++c) acc = __fmaf_rn(W[o * CINP + c], a[c], acc);
        out[obase + (size_t)o * KS] = acc;
        float s1 = acc, s2 = acc * acc;
#pragma unroll
        for (int off = 32; off > 0; off >>= 1) {
            s1 += __shfl_xor(s1, off, 64);
            s2 += __shfl_xor(s2, off, 64);
        }
        if ((tid & 63) == 0) { atomicAdd(&ssum[o], s1); atomicAdd(&ssq[o], s2); }
    }
    __syncthreads();
    if (tid < CO) {
        atomicAdd(&stats[tid], ssum[tid]);
        atomicAdd(&stats[CO + tid], ssq[tid]);
    }
}

// ---------------------------------------------------------------- fused conv
// input-BN (+optional residual) + relu -> GEMM 64x64 -> raw out + stats.
// NOTE: in/idn/act_out/out may ALIAS (in-place use): no __restrict__ on them.
template <bool HAS_IDN, bool WRITE_ACT>
__global__ __launch_bounds__(256) void conv_bn_kernel(const float* in,
                                                      const float* idn,
                                                      const float* __restrict__ stats_in,
                                                      const float* __restrict__ gamma,
                                                      const float* __restrict__ beta,
                                                      const float* __restrict__ W,
                                                      float* act_out,
                                                      float* out,
                                                      float* __restrict__ stats_out) {
    const int p = blockIdx.x * 256 + threadIdx.x;
    const int b = p >> 16;
    const int q = p & 65535;
    const int tid = threadIdx.x;

    __shared__ float ssc[CO], ssh[CO], ssum[CO], ssq[CO];
    if (tid < CO) {
        const float Minv = 1.0f / MCNT;
        float m = stats_in[tid] * Minv;
        float v = stats_in[CO + tid] * Minv - m * m;
        float scl = gamma[tid] * rsqrtf(v + BNEPS);
        ssc[tid] = scl;
        ssh[tid] = beta[tid] - m * scl;
        ssum[tid] = 0.f; ssq[tid] = 0.f;
    }
    __syncthreads();

    const size_t base = (size_t)b * CO * KS + q;
    float a[CO];
#pragma unroll
    for (int c = 0; c < CO; ++c) {
        float v = __fmaf_rn(ssc[c], in[base + (size_t)c * KS], ssh[c]);
        if (HAS_IDN) v += idn[base + (size_t)c * KS];
        v = fmaxf(v, 0.0f);
        a[c] = v;
        if (WRITE_ACT) act_out[base + (size_t)c * KS] = v;
    }
    for (int o = 0; o < CO; ++o) {
        float acc = 0.f;
#pragma unroll
        for (int c = 0; c < CO; ++c) acc = __fmaf_rn(W[o * CO + c], a[c], acc);
        out[base + (size_t)o * KS] = acc;
        float s1 = acc, s2 = acc * acc;
#pragma unroll
        for (int off = 32; off > 0; off >>= 1) {
            s1 += __shfl_xor(s1, off, 64);
            s2 += __shfl_xor(s2, off, 64);
        }
        if ((tid & 63) == 0) { atomicAdd(&ssum[o], s1); atomicAdd(&ssq[o], s2); }
    }
    __syncthreads();
    if (tid < CO) {
        atomicAdd(&stats_out[tid], ssum[tid]);
        atomicAdd(&stats_out[CO + tid], ssq[tid]);
    }
}

// ---------------------------------------------------------------- final
// BN + residual + relu + maxpool over k.
__global__ __launch_bounds__(256) void final_kernel(const float* __restrict__ y2,
                                                    const float* __restrict__ idn,
                                                    const float* __restrict__ stats,
                                                    const float* __restrict__ gamma,
                                                    const float* __restrict__ beta,
                                                    float* __restrict__ feat) {
    const int p = blockIdx.x * 256 + threadIdx.x;   // 0..524287
    const int s = p & 2047;
    const int o = (p >> 11) & 63;
    const int b = p >> 17;
    const float Minv = 1.0f / MCNT;
    float m = stats[o] * Minv;
    float v = stats[CO + o] * Minv - m * m;
    float scl = gamma[o] * rsqrtf(v + BNEPS);
    float sh  = beta[o] - m * scl;
    const size_t base = (size_t)b * CO * KS + (size_t)o * KS + s;
    float mx = -1e30f;
#pragma unroll
    for (int k = 0; k < KNB; ++k) {
        float val = __fmaf_rn(scl, y2[base + (size_t)k * NPT], sh) + idn[base + (size_t)k * NPT];
        val = fmaxf(val, 0.0f);
        mx = fmaxf(mx, val);
    }
    feat[p] = mx;
}

__global__ void zero_kernel(float* p, int n) {
    int i = blockIdx.x * blockDim.x + threadIdx.x;
    if (i < n) p[i] = 0.f;
}

extern "C" void kernel_launch(void* const* d_in, const int* in_sizes, int n_in,
                              void* d_out, int out_size, void* d_ws, size_t ws_size,
                              hipStream_t stream) {
    (void)in_sizes; (void)n_in; (void)out_size; (void)ws_size;
    const float* xyz    = (const float*)d_in[0];
    const float* points = (const float*)d_in[1];
    const float* proj_w = (const float*)d_in[2];
    const float* proj_g = (const float*)d_in[3];
    const float* proj_b = (const float*)d_in[4];
    const float* w1     = (const float*)d_in[5];   // (2,64,64)
    const float* g1     = (const float*)d_in[6];
    const float* b1     = (const float*)d_in[7];
    const float* w2     = (const float*)d_in[8];
    const float* g2     = (const float*)d_in[9];
    const float* b2     = (const float*)d_in[10];

    float* out0 = (float*)d_out;                   // (4,3,2048)
    float* feat = (float*)d_out + NB * 3 * NPT;    // (4,64,2048)

    float* stats = (float*)d_ws;                    // 5 x 128 (rounded to 1024)
    int*   idx   = (int*)((float*)d_ws + 1024);     // (4,2048,32)
    float* A     = (float*)(idx + NB * NPT * KNB);  // activation tensor
    float* B     = A + TELEM;                       // residual tensor

    // fps LDS: cloud 96K + so 24K + skey 128B + swin 16B = 123,024 B
    const size_t fps_lds = (size_t)(3 * NPTS + 3 * NPT) * sizeof(float)
                         + FWAVES * sizeof(unsigned long long)
                         + 4 * sizeof(float);

    hipLaunchKernelGGL(zero_kernel, dim3(3), dim3(256), 0, stream, stats, 5 * 2 * CO);
    hipLaunchKernelGGL(fps_kernel, dim3(NB), dim3(FTHR), fps_lds, stream, xyz, out0);
    hipLaunchKernelGGL(ballq_kernel, dim3(2048), dim3(256), 0, stream, xyz, out0, idx);
    // proj raw conv -> A, stats0
    hipLaunchKernelGGL(proj_kernel, dim3(1024), dim3(256), 0, stream,
                       xyz, points, out0, idx, proj_w, A, stats);
    // d=0: x = relu(bnP(A)); idn0 -> B; y1 -> A (in-place)
    hipLaunchKernelGGL((conv_bn_kernel<false, true>), dim3(1024), dim3(256), 0, stream,
                       A, (const float*)nullptr, stats, proj_g, proj_b, w1,
                       B, A, stats + 128);
    // d=0: y2 = conv(w2[0], relu(bn1(y1)))  A -> A
    hipLaunchKernelGGL((conv_bn_kernel<false, false>), dim3(1024), dim3(256), 0, stream,
                       A, (const float*)nullptr, stats + 128, g1, b1, w2,
                       (float*)nullptr, A, stats + 256);
    // d=1: x = relu(bn2(y2)+idn0); idn1 -> B (aliases idn read); y1 -> A
    hipLaunchKernelGGL((conv_bn_kernel<true, true>), dim3(1024), dim3(256), 0, stream,
                       A, B, stats + 256, g2, b2, w1 + CO * CO,
                       B, A, stats + 384);
    // d=1: y2 = conv(w2[1], relu(bn1'(y1)))  A -> A
    hipLaunchKernelGGL((conv_bn_kernel<false, false>), dim3(1024), dim3(256), 0, stream,
                       A, (const float*)nullptr, stats + 384, g1 + CO, b1 + CO, w2 + CO * CO,
                       (float*)nullptr, A, stats + 512);
    // feat = max_k relu(bn2'(A)+B)
    hipLaunchKernelGGL(final_kernel, dim3(2048), dim3(256), 0, stream,
                       A, B, stats + 512, g2 + CO, b2 + CO, feat);
}